// Round 10
// baseline (181.992 us; speedup 1.0000x reference)
//
#include <hip/hip_runtime.h>
#include <math.h>

#define MOM 0.999f
#define ONE_M_MOM 0.001f
#define INV_TEMP (1.0f / 0.07f)
#define C_CLASSES 20000
#define B_SZ 512
#define DE 512
#define PART_ROW 2048                       // K * Dp = 8 * 256
#define PART_BANK_N (C_CLASSES * PART_ROW)  // 40,960,000 floats
#define EMB_BANK_N (C_CLASSES * DE)         // 10,240,000 floats
#define NEG_INF (-3.0e38f)
#define NTILE 157         // ceil(20000/128) -> per-tile top-16 lists per row
#define NGEMM (4 * NTILE) // 628 gemm blocks

typedef __attribute__((ext_vector_type(8))) short short8;
typedef __attribute__((ext_vector_type(4))) float f32x4;

__device__ inline unsigned short f2bf_rne(float f) {
    unsigned u = __builtin_bit_cast(unsigned, f);
    return (unsigned short)((u + 0x7FFFu + ((u >> 16) & 1u)) >> 16);
}

__device__ inline float bf2f(unsigned short u) {
    return __builtin_bit_cast(float, (unsigned)u << 16);
}

__device__ inline void gload16(const void* g, void* l) {
    __builtin_amdgcn_global_load_lds(
        (const __attribute__((address_space(1))) unsigned int*)g,
        (__attribute__((address_space(3))) unsigned int*)l, 16, 0, 0);
}

// --------- K1: blocks [0,5000): embed bank rows (copy/EMA + norm + bf16)
//               blocks [5000,5128): qnorm -> Ab bf16. Block 0 zeroes counter.
__global__ void __launch_bounds__(256)
embed_qnorm(const float* __restrict__ ebank, const float* __restrict__ emb,
            const int* __restrict__ labels, float* __restrict__ out_eb,
            unsigned short* __restrict__ Bb, float* __restrict__ inv_norm,
            unsigned short* __restrict__ Ab, int* __restrict__ counter) {
    int blk = blockIdx.x;
    int t = threadIdx.x;
    if (blk == 0 && t == 0) *counter = 0;
    int w = t >> 6, l = t & 63;
    if (blk < 5000) {
        // ---------------- embed bank row: copy/EMA + norm + bf16 ----------------
        int c = blk * 4 + w;  // < 20000
        int m = -1;
#pragma unroll
        for (int k = 0; k < 8; ++k)
            if (labels[l + k * 64] == c) m = l + k * 64;
#pragma unroll
        for (int off = 32; off; off >>= 1) m = max(m, __shfl_xor(m, off));

        const float4* row = (const float4*)(ebank + ((long)c << 9));
        float4 v0 = row[2 * l], v1 = row[2 * l + 1];
        if (m >= 0) {
            const float4* nr = (const float4*)(emb + ((long)m << 9));
            float4 n0 = nr[2 * l], n1 = nr[2 * l + 1];
            v0.x = MOM * v0.x + ONE_M_MOM * n0.x;
            v0.y = MOM * v0.y + ONE_M_MOM * n0.y;
            v0.z = MOM * v0.z + ONE_M_MOM * n0.z;
            v0.w = MOM * v0.w + ONE_M_MOM * n0.w;
            v1.x = MOM * v1.x + ONE_M_MOM * n1.x;
            v1.y = MOM * v1.y + ONE_M_MOM * n1.y;
            v1.z = MOM * v1.z + ONE_M_MOM * n1.z;
            v1.w = MOM * v1.w + ONE_M_MOM * n1.w;
        }
        float4* orow = (float4*)(out_eb + ((long)c << 9));
        orow[2 * l] = v0; orow[2 * l + 1] = v1;
        float ss = v0.x * v0.x + v0.y * v0.y + v0.z * v0.z + v0.w * v0.w
                 + v1.x * v1.x + v1.y * v1.y + v1.z * v1.z + v1.w * v1.w;
#pragma unroll
        for (int off = 32; off; off >>= 1) ss += __shfl_xor(ss, off);
        if (l == 0) inv_norm[c] = 1.0f / fmaxf(sqrtf(ss), 1e-12f);
        short8 o;
        o[0] = (short)f2bf_rne(v0.x); o[1] = (short)f2bf_rne(v0.y);
        o[2] = (short)f2bf_rne(v0.z); o[3] = (short)f2bf_rne(v0.w);
        o[4] = (short)f2bf_rne(v1.x); o[5] = (short)f2bf_rne(v1.y);
        o[6] = (short)f2bf_rne(v1.z); o[7] = (short)f2bf_rne(v1.w);
        *(short8*)(Bb + ((long)c << 9) + l * 8) = o;
    } else {
        // ---------------- qnorm -> Ab bf16 ----------------
        int b = (blk - 5000) * 4 + w;  // < 512
        const float4* row = (const float4*)(emb + ((long)b << 9));
        float4 v0 = row[2 * l], v1 = row[2 * l + 1];
        float ss = v0.x * v0.x + v0.y * v0.y + v0.z * v0.z + v0.w * v0.w
                 + v1.x * v1.x + v1.y * v1.y + v1.z * v1.z + v1.w * v1.w;
#pragma unroll
        for (int off = 32; off; off >>= 1) ss += __shfl_xor(ss, off);
        float inv = 1.0f / fmaxf(sqrtf(ss), 1e-12f);
        v0.x *= inv; v0.y *= inv; v0.z *= inv; v0.w *= inv;
        v1.x *= inv; v1.y *= inv; v1.z *= inv; v1.w *= inv;
        short8 o;
        o[0] = (short)f2bf_rne(v0.x); o[1] = (short)f2bf_rne(v0.y);
        o[2] = (short)f2bf_rne(v0.z); o[3] = (short)f2bf_rne(v0.w);
        o[4] = (short)f2bf_rne(v1.x); o[5] = (short)f2bf_rne(v1.y);
        o[6] = (short)f2bf_rne(v1.z); o[7] = (short)f2bf_rne(v1.w);
        *(short8*)(Ab + ((long)b << 9) + l * 8) = o;
    }
}

// --------- K2: blocks [0,NGEMM) MFMA GEMM + per-tile top-16;
//               blocks [NGEMM, NGEMM+512): part-bank EMA fixup of labeled rows
__global__ void __launch_bounds__(256)
gemm_topk(const unsigned short* __restrict__ A, const unsigned short* __restrict__ B,
          const float* __restrict__ inv_norm, const int* __restrict__ labels,
          float* __restrict__ partials,
          const float4* __restrict__ pb, const float4* __restrict__ pf4,
          float4* __restrict__ out_pb) {
    if (blockIdx.x >= NGEMM) {
        // labeled-row EMA fixup: overwrite the copied row (labels are distinct)
        int b = blockIdx.x - NGEMM;  // batch index 0..511
        int t = threadIdx.x;         // 256
        int lab = labels[b];
        const float4* so = pb + ((long)lab << 9);    // 512 float4 per row
        const float4* sn = pf4 + ((long)b << 9);
        float4* dp = out_pb + ((long)lab << 9);
        float4 o0 = so[t], o1 = so[t + 256];
        float4 n0 = sn[t], n1 = sn[t + 256];
        float4 r0, r1;
        r0.x = MOM * o0.x + ONE_M_MOM * n0.x;
        r0.y = MOM * o0.y + ONE_M_MOM * n0.y;
        r0.z = MOM * o0.z + ONE_M_MOM * n0.z;
        r0.w = MOM * o0.w + ONE_M_MOM * n0.w;
        r1.x = MOM * o1.x + ONE_M_MOM * n1.x;
        r1.y = MOM * o1.y + ONE_M_MOM * n1.y;
        r1.z = MOM * o1.z + ONE_M_MOM * n1.z;
        r1.w = MOM * o1.w + ONE_M_MOM * n1.w;
        dp[t] = r0; dp[t + 256] = r1;
        return;
    }

    __shared__ unsigned short smem[128 * 130];  // 33,280 B
    unsigned short* Asm = smem;          // 128 rows x 64 k = 16 KB
    unsigned short* Bsm = smem + 8192;   // 16 KB

    const int t = threadIdx.x;
    const int w = t >> 6, l = t & 63;
    const int wr = w >> 1, wc = w & 1;

    // bijective XCD-chunked remap of 628 gemm blocks (8 XCDs; q=78, r=4)
    int id = blockIdx.x;
    int xcd = id & 7, idx = id >> 3;
    int wg = (xcd < 4) ? xcd * 79 + idx : 316 + (xcd - 4) * 78 + idx;
    const int bm = wg & 3, bn = wg >> 2;

    f32x4 acc[4][4] = {};

    const int srow = t >> 3;                           // 0..31
    const long swz = ((t & 7) ^ (srow & 7)) << 3;      // pre-swizzled source offset
    const unsigned short* Ag = A + ((long)(bm * 128 + srow) << 9) + swz;
    const unsigned short* Bg[4];
#pragma unroll
    for (int i = 0; i < 4; ++i) {
        int br = bn * 128 + i * 32 + srow;
        if (br > C_CLASSES - 1) br = C_CLASSES - 1;
        Bg[i] = B + ((long)br << 9) + swz;
    }
    char* Adst = (char*)Asm + (w << 10);
    char* Bdst = (char*)Bsm + (w << 10);

    const int fr = l & 15;
    const int s4 = l >> 4;  // 0..3
    const int swr0 = ((s4) ^ (fr & 7)) << 4;
    const int swr1 = ((4 + s4) ^ (fr & 7)) << 4;

    for (int kt = 0; kt < 8; ++kt) {
        const int ko = kt << 6;
#pragma unroll
        for (int i = 0; i < 4; ++i) {
            gload16(Ag + ko + ((long)i << 14), Adst + (i << 12));
            gload16(Bg[i] + ko, Bdst + (i << 12));
        }
        __syncthreads();
        short8 af[2][4], bf[2][4];
        const char* Abase = (const char*)Asm;
        const char* Bbase = (const char*)Bsm;
#pragma unroll
        for (int m = 0; m < 4; ++m) {
            int ra = (wr * 64 + m * 16 + fr) << 7;
            int rb = (wc * 64 + m * 16 + fr) << 7;
            af[0][m] = *(const short8*)(Abase + ra + swr0);
            af[1][m] = *(const short8*)(Abase + ra + swr1);
            bf[0][m] = *(const short8*)(Bbase + rb + swr0);
            bf[1][m] = *(const short8*)(Bbase + rb + swr1);
        }
        __builtin_amdgcn_s_setprio(1);
#pragma unroll
        for (int kk = 0; kk < 2; ++kk)
#pragma unroll
            for (int m = 0; m < 4; ++m)
#pragma unroll
                for (int n = 0; n < 4; ++n)
                    acc[m][n] = __builtin_amdgcn_mfma_f32_16x16x32_bf16(
                        af[kk][m], bf[kk][n], acc[m][n], 0, 0, 0);
        __builtin_amdgcn_s_setprio(0);
        __syncthreads();
    }

    // ---- dump scaled sim into bf16 stile (C/D: col=lane&15, row=(lane>>4)*4+j)
    unsigned short* stile = smem;  // [128][130] bf16
    const int r4 = s4 << 2;
#pragma unroll
    for (int n = 0; n < 4; ++n) {
        int ct = wc * 64 + fr + n * 16;
        int cg = bn * 128 + ct;
        bool ok = cg < C_CLASSES;
        float sc = ok ? inv_norm[cg] * INV_TEMP : 0.0f;
#pragma unroll
        for (int m = 0; m < 4; ++m) {
            int rt = wr * 64 + r4 + m * 16;
#pragma unroll
            for (int j = 0; j < 4; ++j) {
                float v = ok ? acc[m][n][j] * sc : NEG_INF;
                stile[(rt + j) * 130 + ct] = f2bf_rne(v);
            }
        }
    }
    __syncthreads();

    // ---- per-row half-tile top-16 (sorted desc), then partner-merge to per-tile
    const int r = t >> 1, half = t & 1;
    const int gr = bm * 128 + r;
    const int lab = labels[gr];
    const int lab_l = lab - (bn << 7) - (half << 6);
    const unsigned short* bp = stile + r * 130 + half * 64;
    float tl[16];
#pragma unroll
    for (int j = 0; j < 16; ++j) tl[j] = NEG_INF;
    for (int c = 0; c < 64; ++c) {
        if (c == lab_l) continue;
        float v = bf2f(bp[c]);
        if (v > tl[15]) {
            tl[15] = v;
#pragma unroll
            for (int j = 15; j > 0; --j) {
                float a = tl[j - 1], bb = tl[j];
                if (bb > a) { tl[j - 1] = bb; tl[j] = a; }
            }
        }
    }
    // bitonic half-cleaner: top-16 of (tl ∪ partner's tl) = max(tl[i], ol[15-i])
    float ol[16];
#pragma unroll
    for (int j = 0; j < 16; ++j) ol[j] = __shfl_xor(tl[j], 1);
    if (half == 0) {
        float4 o0, o1, o2, o3;
        o0.x = fmaxf(tl[0],  ol[15]); o0.y = fmaxf(tl[1],  ol[14]);
        o0.z = fmaxf(tl[2],  ol[13]); o0.w = fmaxf(tl[3],  ol[12]);
        o1.x = fmaxf(tl[4],  ol[11]); o1.y = fmaxf(tl[5],  ol[10]);
        o1.z = fmaxf(tl[6],  ol[9]);  o1.w = fmaxf(tl[7],  ol[8]);
        o2.x = fmaxf(tl[8],  ol[7]);  o2.y = fmaxf(tl[9],  ol[6]);
        o2.z = fmaxf(tl[10], ol[5]);  o2.w = fmaxf(tl[11], ol[4]);
        o3.x = fmaxf(tl[12], ol[3]);  o3.y = fmaxf(tl[13], ol[2]);
        o3.z = fmaxf(tl[14], ol[1]);  o3.w = fmaxf(tl[15], ol[0]);
        float4* op4 = (float4*)(partials + ((long)gr * NTILE + bn) * 16);
        op4[0] = o0; op4[1] = o1; op4[2] = o2; op4[3] = o3;
    }
}

// --------- K3: one wave/row merge + logsumexp + align; last block finalizes means
__global__ void __launch_bounds__(64)
merge_fin(const float* __restrict__ partials, const float* __restrict__ emb,
          const float* __restrict__ out_eb, const float* __restrict__ sat,
          const float* __restrict__ inv_norm, const int* __restrict__ labels,
          float* __restrict__ lnce, float* __restrict__ lalign,
          int* __restrict__ counter, float* __restrict__ out_losses) {
    int b = blockIdx.x;
    int l = threadIdx.x;  // 64
    const float4* pr4 = (const float4*)(partials + (long)b * (NTILE * 16));

    float tl[16];
#pragma unroll
    for (int j = 0; j < 16; ++j) tl[j] = NEG_INF;
    for (int i = l; i < NTILE * 4; i += 64) {   // 628 float4
        float4 v4 = pr4[i];
        float vv[4] = {v4.x, v4.y, v4.z, v4.w};
#pragma unroll
        for (int q = 0; q < 4; ++q) {
            float v = vv[q];
            if (v > tl[15]) {
                tl[15] = v;
#pragma unroll
                for (int j = 15; j > 0; --j) {
                    float a = tl[j - 1], bb = tl[j];
                    if (bb > a) { tl[j - 1] = bb; tl[j] = a; }
                }
            }
        }
    }

    // 16 rounds of wave-max extraction; logsumexp accumulated in-register
    float M = 0.f, S = 0.f;
#pragma unroll 1
    for (int j = 0; j < 16; ++j) {
        float v = tl[0];
        float mx = v;
#pragma unroll
        for (int off = 32; off; off >>= 1) mx = fmaxf(mx, __shfl_xor(mx, off));
        unsigned long long ball = __ballot(v == mx);
        int win = (int)(__ffsll((unsigned long long)ball)) - 1;
        if (l == win) {
#pragma unroll
            for (int q = 0; q < 15; ++q) tl[q] = tl[q + 1];
            tl[15] = NEG_INF;
        }
        if (j == 0) { M = mx; S = 1.0f; }
        else S += expf(mx - M);
    }

    // four fp32 dots: emb.e, sat.e, sat.sat, emb.emb
    int lab = labels[b];
    const float4* qr = (const float4*)(emb + ((long)b << 9));
    const float4* er = (const float4*)(out_eb + ((long)lab << 9));
    const float4* sr = (const float4*)(sat + ((long)b << 9));
    float a1 = 0.f, a2 = 0.f, a3 = 0.f, a4 = 0.f;
#pragma unroll
    for (int rr = 0; rr < 2; ++rr) {
        int j = 2 * l + rr;
        float4 d4 = qr[j], s4 = sr[j], e4 = er[j];
        a1 += d4.x * e4.x + d4.y * e4.y + d4.z * e4.z + d4.w * e4.w;
        a2 += s4.x * e4.x + s4.y * e4.y + s4.z * e4.z + s4.w * e4.w;
        a3 += s4.x * s4.x + s4.y * s4.y + s4.z * s4.z + s4.w * s4.w;
        a4 += d4.x * d4.x + d4.y * d4.y + d4.z * d4.z + d4.w * d4.w;
    }
#pragma unroll
    for (int off = 32; off; off >>= 1) {
        a1 += __shfl_xor(a1, off);
        a2 += __shfl_xor(a2, off);
        a3 += __shfl_xor(a3, off);
        a4 += __shfl_xor(a4, off);
    }
    int done = 0;
    if (l == 0) {
        float invl = inv_norm[lab];
        float invq = 1.0f / fmaxf(sqrtf(a4), 1e-12f);
        float pos = a1 * invq * invl * INV_TEMP;
        float mx2 = fmaxf(M, pos);
        float ssum = expf(M - mx2) * S + expf(pos - mx2);
        lnce[b] = logf(ssum) + mx2 - pos;
        float pd = a1 * invq * invl;
        float ps = a2 * invl / fmaxf(sqrtf(a3), 1e-12f);
        lalign[b] = 1.0f - 0.5f * (pd + ps);
        __threadfence();
        done = (atomicAdd(counter, 1) == B_SZ - 1) ? 1 : 0;
    }
    done = __shfl(done, 0);
    if (done) {
        __threadfence();
        volatile const float* vn = lnce;
        volatile const float* va = lalign;
        float s1 = 0.f, s2 = 0.f;
#pragma unroll
        for (int k = 0; k < B_SZ / 64; ++k) {
            s1 += vn[l + k * 64];
            s2 += va[l + k * 64];
        }
#pragma unroll
        for (int off = 32; off; off >>= 1) {
            s1 += __shfl_xor(s1, off);
            s2 += __shfl_xor(s2, off);
        }
        if (l == 0) {
            out_losses[0] = s1 / (float)B_SZ;
            out_losses[1] = s2 / (float)B_SZ;
            *counter = 0;  // reset for next replay
        }
    }
}

extern "C" void kernel_launch(void* const* d_in, const int* in_sizes, int n_in,
                              void* d_out, int out_size, void* d_ws, size_t ws_size,
                              hipStream_t stream) {
    const float* pf = (const float*)d_in[0];
    const float* emb = (const float*)d_in[1];
    const float* sat = (const float*)d_in[2];
    const float* pb = (const float*)d_in[3];
    const float* ebank = (const float*)d_in[4];
    const int* labels = (const int*)d_in[5];

    float* out = (float*)d_out;
    float* out_pb = out;
    float* out_eb = out + PART_BANK_N;
    float* out_losses = out + PART_BANK_N + EMB_BANK_N;

    // ws layout (floats):
    // inv_norm 20,000 | counter 16(int) | lnce 512 | lalign 512
    // | partials 512*157*16 = 1,285,120 | Ab u16 262,144 | Bb u16 10,240,000
    float* ws = (float*)d_ws;
    float* inv_norm = ws;
    int* counter = (int*)(inv_norm + C_CLASSES);
    float* lnce = (float*)(counter + 16);
    float* lalign = lnce + B_SZ;
    float* partials = lalign + B_SZ;
    unsigned short* Ab = (unsigned short*)(partials + (long)B_SZ * NTILE * 16);
    unsigned short* Bb = Ab + (long)B_SZ * DE;

    // bulk part-bank copy via the runtime's tuned blit/SDMA path
    hipMemcpyAsync(out_pb, pb, (size_t)PART_BANK_N * sizeof(float),
                   hipMemcpyDeviceToDevice, stream);
    embed_qnorm<<<5000 + 128, 256, 0, stream>>>(ebank, emb, labels, out_eb, Bb,
                                                inv_norm, Ab, counter);
    gemm_topk<<<NGEMM + B_SZ, 256, 0, stream>>>(Ab, Bb, inv_norm, labels, partials,
                                                (const float4*)pb, (const float4*)pf,
                                                (float4*)out_pb);
    merge_fin<<<B_SZ, 64, 0, stream>>>(partials, emb, out_eb, sat, inv_norm,
                                       labels, lnce, lalign, counter, out_losses);
}

// Round 11
// 131.187 us; speedup vs baseline: 1.3873x; 1.3873x over previous
//
#include <hip/hip_runtime.h>
#include <math.h>

#define MOM 0.999f
#define ONE_M_MOM 0.001f
#define INV_TEMP (1.0f / 0.07f)
#define C_CLASSES 20000
#define B_SZ 512
#define DE 512
#define PART_ROW 2048                       // K * Dp = 8 * 256
#define PART_BANK_N (C_CLASSES * PART_ROW)  // 40,960,000 floats
#define EMB_BANK_N (C_CLASSES * DE)         // 10,240,000 floats
#define NEG_INF (-3.0e38f)
#define NTILE 157         // ceil(20000/128) -> per-tile top-16 lists per row
#define NGEMM (4 * NTILE) // 628 gemm blocks
#define NCHUNK 2500       // part chunks (8 rows each), one block each

typedef __attribute__((ext_vector_type(8))) short short8;
typedef __attribute__((ext_vector_type(4))) float f32x4;

__device__ inline unsigned short f2bf_rne(float f) {
    unsigned u = __builtin_bit_cast(unsigned, f);
    return (unsigned short)((u + 0x7FFFu + ((u >> 16) & 1u)) >> 16);
}

__device__ inline float bf2f(unsigned short u) {
    return __builtin_bit_cast(float, (unsigned)u << 16);
}

__device__ inline void gload16(const void* g, void* l) {
    __builtin_amdgcn_global_load_lds(
        (const __attribute__((address_space(1))) unsigned int*)g,
        (__attribute__((address_space(3))) unsigned int*)l, 16, 0, 0);
}

// --------- K1: blocks [0,5000): embed bank rows (copy/EMA + norm), no bf16 bank;
//               blocks [5000,5128): qnorm -> Ab bf16. Block 0 zeroes counter.
__global__ void __launch_bounds__(256)
embed_qnorm(const float* __restrict__ ebank, const float* __restrict__ emb,
            const int* __restrict__ labels, float* __restrict__ out_eb,
            float* __restrict__ inv_norm, unsigned short* __restrict__ Ab,
            int* __restrict__ counter) {
    int blk = blockIdx.x;
    int t = threadIdx.x;
    if (blk == 0 && t == 0) *counter = 0;
    int w = t >> 6, l = t & 63;
    if (blk < 5000) {
        int c = blk * 4 + w;  // < 20000
        int m = -1;
#pragma unroll
        for (int k = 0; k < 8; ++k)
            if (labels[l + k * 64] == c) m = l + k * 64;
#pragma unroll
        for (int off = 32; off; off >>= 1) m = max(m, __shfl_xor(m, off));

        const float4* row = (const float4*)(ebank + ((long)c << 9));
        float4 v0 = row[2 * l], v1 = row[2 * l + 1];
        if (m >= 0) {
            const float4* nr = (const float4*)(emb + ((long)m << 9));
            float4 n0 = nr[2 * l], n1 = nr[2 * l + 1];
            v0.x = MOM * v0.x + ONE_M_MOM * n0.x;
            v0.y = MOM * v0.y + ONE_M_MOM * n0.y;
            v0.z = MOM * v0.z + ONE_M_MOM * n0.z;
            v0.w = MOM * v0.w + ONE_M_MOM * n0.w;
            v1.x = MOM * v1.x + ONE_M_MOM * n1.x;
            v1.y = MOM * v1.y + ONE_M_MOM * n1.y;
            v1.z = MOM * v1.z + ONE_M_MOM * n1.z;
            v1.w = MOM * v1.w + ONE_M_MOM * n1.w;
        }
        float4* orow = (float4*)(out_eb + ((long)c << 9));
        orow[2 * l] = v0; orow[2 * l + 1] = v1;
        float ss = v0.x * v0.x + v0.y * v0.y + v0.z * v0.z + v0.w * v0.w
                 + v1.x * v1.x + v1.y * v1.y + v1.z * v1.z + v1.w * v1.w;
#pragma unroll
        for (int off = 32; off; off >>= 1) ss += __shfl_xor(ss, off);
        if (l == 0) inv_norm[c] = 1.0f / fmaxf(sqrtf(ss), 1e-12f);
    } else {
        int b = (blk - 5000) * 4 + w;  // < 512
        const float4* row = (const float4*)(emb + ((long)b << 9));
        float4 v0 = row[2 * l], v1 = row[2 * l + 1];
        float ss = v0.x * v0.x + v0.y * v0.y + v0.z * v0.z + v0.w * v0.w
                 + v1.x * v1.x + v1.y * v1.y + v1.z * v1.z + v1.w * v1.w;
#pragma unroll
        for (int off = 32; off; off >>= 1) ss += __shfl_xor(ss, off);
        float inv = 1.0f / fmaxf(sqrtf(ss), 1e-12f);
        v0.x *= inv; v0.y *= inv; v0.z *= inv; v0.w *= inv;
        v1.x *= inv; v1.y *= inv; v1.z *= inv; v1.w *= inv;
        short8 o;
        o[0] = (short)f2bf_rne(v0.x); o[1] = (short)f2bf_rne(v0.y);
        o[2] = (short)f2bf_rne(v0.z); o[3] = (short)f2bf_rne(v0.w);
        o[4] = (short)f2bf_rne(v1.x); o[5] = (short)f2bf_rne(v1.y);
        o[6] = (short)f2bf_rne(v1.z); o[7] = (short)f2bf_rne(v1.w);
        *(short8*)(Ab + ((long)b << 9) + l * 8) = o;
    }
}

// --------- K2: blocks [0,NGEMM): MFMA GEMM (B reg-staged from fp32) + top-16;
//               blocks [NGEMM, NGEMM+2500): part bank 8-row copy/EMA (nontemporal)
__global__ void __launch_bounds__(256)
part_gemm(const unsigned short* __restrict__ A, const float* __restrict__ out_eb,
          const float* __restrict__ inv_norm, const int* __restrict__ labels,
          float* __restrict__ partials,
          const float* __restrict__ pb, const float* __restrict__ pf,
          float* __restrict__ out_pb) {
    __shared__ unsigned short smem[128 * 130];  // 33,280 B (shared by both paths)

    if (blockIdx.x >= NGEMM) {
        // ---------------- part bank: 8 rows per block, copy/EMA ----------------
        int c0 = (blockIdx.x - NGEMM) * 8;
        int t = threadIdx.x;   // 256
        int* mbs = (int*)smem; // [8]
        if (t < 8) mbs[t] = -1;
        __syncthreads();
        int la = labels[t], lb = labels[t + 256];
#pragma unroll
        for (int r = 0; r < 8; ++r) {
            if (la == c0 + r) mbs[r] = t;
            if (lb == c0 + r) mbs[r] = t + 256;
        }
        __syncthreads();
        const f32x4* src = (const f32x4*)pb + (long)c0 * (PART_ROW / 4);
        f32x4* dst = (f32x4*)out_pb + (long)c0 * (PART_ROW / 4);
        const f32x4* pf4 = (const f32x4*)pf;
        f32x4 v[16];
#pragma unroll
        for (int i = 0; i < 16; ++i)
            v[i] = __builtin_nontemporal_load(&src[t + i * 256]);  // row = i>>1
#pragma unroll
        for (int i = 0; i < 16; ++i) {
            int mb = mbs[i >> 1];  // wave-uniform
            if (mb >= 0) {
                f32x4 n = pf4[(long)mb * (PART_ROW / 4) + (t + (i & 1) * 256)];
                v[i] = MOM * v[i] + ONE_M_MOM * n;
            }
            __builtin_nontemporal_store(v[i], &dst[t + i * 256]);
        }
        return;
    }

    // ---------------- GEMM tile + fused top-16 ----------------
    unsigned short* Asm = smem;          // 128 rows x 64 k = 16 KB
    unsigned short* Bsm = smem + 8192;   // 16 KB

    const int t = threadIdx.x;
    const int w = t >> 6, l = t & 63;
    const int wr = w >> 1, wc = w & 1;

    // bijective XCD-chunked remap of 628 gemm blocks (8 XCDs; q=78, r=4)
    int id = blockIdx.x;
    int xcd = id & 7, idx = id >> 3;
    int wg = (xcd < 4) ? xcd * 79 + idx : 316 + (xcd - 4) * 78 + idx;
    const int bm = wg & 3, bn = wg >> 2;

    f32x4 acc[4][4] = {};

    // A staging: srow = t>>3 (0..31), slot = t&7, source k pre-swizzled
    const int srow = t >> 3;
    const long swz = ((t & 7) ^ (srow & 7)) << 3;
    const unsigned short* Ag = A + ((long)(bm * 128 + srow) << 9) + swz;
    char* Adst = (char*)Asm + (w << 10);

    // B staging: reg-stage from out_eb fp32, convert, swizzled ds_write
    const int brow = t >> 1;   // 0..127
    const int bh = t & 1;      // k-half (32 floats)
    int gbr = bn * 128 + brow; if (gbr > C_CLASSES - 1) gbr = C_CLASSES - 1;
    const float4* Bsrc = (const float4*)out_eb + ((long)gbr << 7);  // 128 f4/row
    unsigned short* Bwp = Bsm + (brow << 6);  // 64 bf16 per row

    const int fr = l & 15;
    const int s4 = l >> 4;  // 0..3
    const int swr0 = ((s4) ^ (fr & 7)) << 4;
    const int swr1 = ((4 + s4) ^ (fr & 7)) << 4;

    for (int kt = 0; kt < 8; ++kt) {
        const int ko = kt << 6;
#pragma unroll
        for (int i = 0; i < 4; ++i)
            gload16(Ag + ko + ((long)i << 14), Adst + (i << 12));
        // B: load 32 floats, convert to bf16, swizzled ds_write
        float4 bv[8];
#pragma unroll
        for (int i = 0; i < 8; ++i) bv[i] = Bsrc[kt * 16 + bh * 8 + i];
#pragma unroll
        for (int s = 0; s < 4; ++s) {
            short8 o;
            float4 x0 = bv[2 * s], x1 = bv[2 * s + 1];
            o[0] = (short)f2bf_rne(x0.x); o[1] = (short)f2bf_rne(x0.y);
            o[2] = (short)f2bf_rne(x0.z); o[3] = (short)f2bf_rne(x0.w);
            o[4] = (short)f2bf_rne(x1.x); o[5] = (short)f2bf_rne(x1.y);
            o[6] = (short)f2bf_rne(x1.z); o[7] = (short)f2bf_rne(x1.w);
            int slot = (bh * 4 + s) ^ (brow & 7);
            *(short8*)(Bwp + slot * 8) = o;
        }
        __syncthreads();
        short8 af[2][4], bf[2][4];
        const char* Abase = (const char*)Asm;
        const char* Bbase = (const char*)Bsm;
#pragma unroll
        for (int m = 0; m < 4; ++m) {
            int ra = (wr * 64 + m * 16 + fr) << 7;
            int rb = (wc * 64 + m * 16 + fr) << 7;
            af[0][m] = *(const short8*)(Abase + ra + swr0);
            af[1][m] = *(const short8*)(Abase + ra + swr1);
            bf[0][m] = *(const short8*)(Bbase + rb + swr0);
            bf[1][m] = *(const short8*)(Bbase + rb + swr1);
        }
        __builtin_amdgcn_s_setprio(1);
#pragma unroll
        for (int kk = 0; kk < 2; ++kk)
#pragma unroll
            for (int m = 0; m < 4; ++m)
#pragma unroll
                for (int n = 0; n < 4; ++n)
                    acc[m][n] = __builtin_amdgcn_mfma_f32_16x16x32_bf16(
                        af[kk][m], bf[kk][n], acc[m][n], 0, 0, 0);
        __builtin_amdgcn_s_setprio(0);
        __syncthreads();
    }

    // ---- dump scaled sim into bf16 stile (C/D: col=lane&15, row=(lane>>4)*4+j)
    unsigned short* stile = smem;  // [128][130] bf16
    const int r4 = s4 << 2;
#pragma unroll
    for (int n = 0; n < 4; ++n) {
        int ct = wc * 64 + fr + n * 16;
        int cg = bn * 128 + ct;
        bool ok = cg < C_CLASSES;
        float sc = ok ? inv_norm[cg] * INV_TEMP : 0.0f;
#pragma unroll
        for (int m = 0; m < 4; ++m) {
            int rt = wr * 64 + r4 + m * 16;
#pragma unroll
            for (int j = 0; j < 4; ++j) {
                float v = ok ? acc[m][n][j] * sc : NEG_INF;
                stile[(rt + j) * 130 + ct] = f2bf_rne(v);
            }
        }
    }
    __syncthreads();

    // ---- per-row half-tile top-16 (sorted desc), then partner-merge to per-tile
    const int r = t >> 1, half = t & 1;
    const int gr = bm * 128 + r;
    const int lab = labels[gr];
    const int lab_l = lab - (bn << 7) - (half << 6);
    const unsigned short* bp = stile + r * 130 + half * 64;
    float tl[16];
#pragma unroll
    for (int j = 0; j < 16; ++j) tl[j] = NEG_INF;
    for (int c = 0; c < 64; ++c) {
        if (c == lab_l) continue;
        float v = bf2f(bp[c]);
        if (v > tl[15]) {
            tl[15] = v;
#pragma unroll
            for (int j = 15; j > 0; --j) {
                float a = tl[j - 1], bb = tl[j];
                if (bb > a) { tl[j - 1] = bb; tl[j] = a; }
            }
        }
    }
    // bitonic half-cleaner: top-16 of (tl ∪ partner's tl) = max(tl[i], ol[15-i])
    float ol[16];
#pragma unroll
    for (int j = 0; j < 16; ++j) ol[j] = __shfl_xor(tl[j], 1);
    if (half == 0) {
        float4 o0, o1, o2, o3;
        o0.x = fmaxf(tl[0],  ol[15]); o0.y = fmaxf(tl[1],  ol[14]);
        o0.z = fmaxf(tl[2],  ol[13]); o0.w = fmaxf(tl[3],  ol[12]);
        o1.x = fmaxf(tl[4],  ol[11]); o1.y = fmaxf(tl[5],  ol[10]);
        o1.z = fmaxf(tl[6],  ol[9]);  o1.w = fmaxf(tl[7],  ol[8]);
        o2.x = fmaxf(tl[8],  ol[7]);  o2.y = fmaxf(tl[9],  ol[6]);
        o2.z = fmaxf(tl[10], ol[5]);  o2.w = fmaxf(tl[11], ol[4]);
        o3.x = fmaxf(tl[12], ol[3]);  o3.y = fmaxf(tl[13], ol[2]);
        o3.z = fmaxf(tl[14], ol[1]);  o3.w = fmaxf(tl[15], ol[0]);
        float4* op4 = (float4*)(partials + ((long)gr * NTILE + bn) * 16);
        op4[0] = o0; op4[1] = o1; op4[2] = o2; op4[3] = o3;
    }
}

// --------- K3: one wave/row merge + logsumexp + align; last block finalizes means
__global__ void __launch_bounds__(64)
merge_fin(const float* __restrict__ partials, const float* __restrict__ emb,
          const float* __restrict__ out_eb, const float* __restrict__ sat,
          const float* __restrict__ inv_norm, const int* __restrict__ labels,
          float* __restrict__ lnce, float* __restrict__ lalign,
          int* __restrict__ counter, float* __restrict__ out_losses) {
    int b = blockIdx.x;
    int l = threadIdx.x;  // 64
    const float4* pr4 = (const float4*)(partials + (long)b * (NTILE * 16));

    float tl[16];
#pragma unroll
    for (int j = 0; j < 16; ++j) tl[j] = NEG_INF;
    for (int i = l; i < NTILE * 4; i += 64) {   // 628 float4
        float4 v4 = pr4[i];
        float vv[4] = {v4.x, v4.y, v4.z, v4.w};
#pragma unroll
        for (int q = 0; q < 4; ++q) {
            float v = vv[q];
            if (v > tl[15]) {
                tl[15] = v;
#pragma unroll
                for (int j = 15; j > 0; --j) {
                    float a = tl[j - 1], bb = tl[j];
                    if (bb > a) { tl[j - 1] = bb; tl[j] = a; }
                }
            }
        }
    }

    // 16 rounds of wave-max extraction; logsumexp accumulated in-register
    float M = 0.f, S = 0.f;
#pragma unroll 1
    for (int j = 0; j < 16; ++j) {
        float v = tl[0];
        float mx = v;
#pragma unroll
        for (int off = 32; off; off >>= 1) mx = fmaxf(mx, __shfl_xor(mx, off));
        unsigned long long ball = __ballot(v == mx);
        int win = (int)(__ffsll((unsigned long long)ball)) - 1;
        if (l == win) {
#pragma unroll
            for (int q = 0; q < 15; ++q) tl[q] = tl[q + 1];
            tl[15] = NEG_INF;
        }
        if (j == 0) { M = mx; S = 1.0f; }
        else S += expf(mx - M);
    }

    // four fp32 dots: emb.e, sat.e, sat.sat, emb.emb
    int lab = labels[b];
    const float4* qr = (const float4*)(emb + ((long)b << 9));
    const float4* er = (const float4*)(out_eb + ((long)lab << 9));
    const float4* sr = (const float4*)(sat + ((long)b << 9));
    float a1 = 0.f, a2 = 0.f, a3 = 0.f, a4 = 0.f;
#pragma unroll
    for (int rr = 0; rr < 2; ++rr) {
        int j = 2 * l + rr;
        float4 d4 = qr[j], s4 = sr[j], e4 = er[j];
        a1 += d4.x * e4.x + d4.y * e4.y + d4.z * e4.z + d4.w * e4.w;
        a2 += s4.x * e4.x + s4.y * e4.y + s4.z * e4.z + s4.w * e4.w;
        a3 += s4.x * s4.x + s4.y * s4.y + s4.z * s4.z + s4.w * s4.w;
        a4 += d4.x * d4.x + d4.y * d4.y + d4.z * d4.z + d4.w * d4.w;
    }
#pragma unroll
    for (int off = 32; off; off >>= 1) {
        a1 += __shfl_xor(a1, off);
        a2 += __shfl_xor(a2, off);
        a3 += __shfl_xor(a3, off);
        a4 += __shfl_xor(a4, off);
    }
    int done = 0;
    if (l == 0) {
        float invl = inv_norm[lab];
        float invq = 1.0f / fmaxf(sqrtf(a4), 1e-12f);
        float pos = a1 * invq * invl * INV_TEMP;
        float mx2 = fmaxf(M, pos);
        float ssum = expf(M - mx2) * S + expf(pos - mx2);
        lnce[b] = logf(ssum) + mx2 - pos;
        float pd = a1 * invq * invl;
        float ps = a2 * invl / fmaxf(sqrtf(a3), 1e-12f);
        lalign[b] = 1.0f - 0.5f * (pd + ps);
        __threadfence();
        done = (atomicAdd(counter, 1) == B_SZ - 1) ? 1 : 0;
    }
    done = __shfl(done, 0);
    if (done) {
        __threadfence();
        volatile const float* vn = lnce;
        volatile const float* va = lalign;
        float s1 = 0.f, s2 = 0.f;
#pragma unroll
        for (int k = 0; k < B_SZ / 64; ++k) {
            s1 += vn[l + k * 64];
            s2 += va[l + k * 64];
        }
#pragma unroll
        for (int off = 32; off; off >>= 1) {
            s1 += __shfl_xor(s1, off);
            s2 += __shfl_xor(s2, off);
        }
        if (l == 0) {
            out_losses[0] = s1 / (float)B_SZ;
            out_losses[1] = s2 / (float)B_SZ;
            *counter = 0;  // reset for next replay
        }
    }
}

extern "C" void kernel_launch(void* const* d_in, const int* in_sizes, int n_in,
                              void* d_out, int out_size, void* d_ws, size_t ws_size,
                              hipStream_t stream) {
    const float* pf = (const float*)d_in[0];
    const float* emb = (const float*)d_in[1];
    const float* sat = (const float*)d_in[2];
    const float* pb = (const float*)d_in[3];
    const float* ebank = (const float*)d_in[4];
    const int* labels = (const int*)d_in[5];

    float* out = (float*)d_out;
    float* out_pb = out;
    float* out_eb = out + PART_BANK_N;
    float* out_losses = out + PART_BANK_N + EMB_BANK_N;

    // ws layout (floats):
    // inv_norm 20,000 | counter 16(int) | lnce 512 | lalign 512
    // | partials 512*157*16 = 1,285,120 | Ab u16 262,144
    float* ws = (float*)d_ws;
    float* inv_norm = ws;
    int* counter = (int*)(inv_norm + C_CLASSES);
    float* lnce = (float*)(counter + 16);
    float* lalign = lnce + B_SZ;
    float* partials = lalign + B_SZ;
    unsigned short* Ab = (unsigned short*)(partials + (long)B_SZ * NTILE * 16);

    embed_qnorm<<<5000 + 128, 256, 0, stream>>>(ebank, emb, labels, out_eb,
                                                inv_norm, Ab, counter);
    part_gemm<<<NGEMM + NCHUNK, 256, 0, stream>>>(Ab, out_eb, inv_norm, labels,
                                                  partials, pb, pf, out_pb);
    merge_fin<<<B_SZ, 64, 0, stream>>>(partials, emb, out_eb, sat, inv_norm,
                                       labels, lnce, lalign, counter, out_losses);
}